// Round 1
// 21344.807 us; speedup vs baseline: 1.0538x; 1.0538x over previous
//
#include <hip/hip_runtime.h>
#include <cstdint>
#include <cstddef>

// MinGRU persistent MFMA scan, round 4: barrier-free data-flow handshake.
// 128 blocks x 512 threads. Block j owns h-cols [8j,8j+8) -> gate cols
// {8j..}, {1024+8j..} (N=16 MFMA tile). W slice in LDS (bf16 hi/lo).
// A = [x_t || h]: x from precomputed bf16 hi/mid/lo arrays (plain loads),
// h exchanged via RELAXED agent-scope atomics.
//
// Round-4 change: the grid barrier (tree of atomic RMWs, ~3 serialized L3
// round-trips + contention, every block waits for the LAST block) is
// replaced by per-publisher FLAGS. Publisher wave: 3 data stores ->
// s_waitcnt vmcnt(0) (manual release, no cache-maintenance ops) -> flag
// store (flag value = step tag). Reader wave: each lane polls exactly one
// of the 64 flags covering its k-slice, then issues the identical 48-load
// fetch. 2-slab reuse is race-free: publishing h_{t+1} requires reading
// all of h_t, which requires all blocks published h_t, which requires all
// blocks finished reading h_{t-1} (the slab being overwritten).
// Arithmetic is bit-identical to round 3 (same 3-split h, same packing,
// same MFMA/reduce order) -> absmax unchanged.

#define BB 16
#define SS 2048
#define DD 1024
#define EE 2048
#define NBLK 128
#define NTHR 512
#define WSTR 2056

typedef __attribute__((ext_vector_type(8))) short short8b;
typedef __attribute__((ext_vector_type(4))) float float4v;
typedef unsigned long long u64;
typedef unsigned short u16;

__device__ __forceinline__ u16 f2bf(float f) {
  unsigned u = __float_as_uint(f);
  return (u16)((u + 0x7FFFu + ((u >> 16) & 1u)) >> 16);
}
__device__ __forceinline__ float bf2f(u16 s) { return __uint_as_float(((unsigned)s) << 16); }
__device__ __forceinline__ u64 ald(const u64* p) {
  return __hip_atomic_load(p, __ATOMIC_RELAXED, __HIP_MEMORY_SCOPE_AGENT);
}

// Publish 128 owners' new h (waves 0,1; owner tid = b + 16*pi) as packed
// 3-split bf16, 4 cols per u64, via relaxed agent atomic stores; then each
// publishing wave drains its stores (vmcnt(0)) and posts its step flag.
// flags layout: [2 slab][128 j][2 half] u64 -> linear slab*256 + 2*j + half.
__device__ __forceinline__ void publish_h(u64* hsl, u64* flags, int np, u64 fval,
                                          int j, int tid, float hn) {
  int src = (tid & 15);
  float g1 = __shfl(hn, src + 16, 64);
  float g2 = __shfl(hn, src + 32, 64);
  float g3 = __shfl(hn, src + 48, 64);
  if ((tid & 63) < 16) {
    int b = tid & 15, cg = tid >> 6;   // wave0 -> cols 8j+0..3, wave1 -> 8j+4..7
    float vals[4] = {hn, g1, g2, g3};
    u64 p0 = 0, p1 = 0, p2 = 0;
    #pragma unroll
    for (int i = 0; i < 4; ++i) {
      float f = vals[i];
      u16 a = f2bf(f); float r  = f - bf2f(a);
      u16 m = f2bf(r); float r2 = r - bf2f(m);
      u16 c = f2bf(r2);
      p0 |= (u64)a << (16 * i); p1 |= (u64)m << (16 * i); p2 |= (u64)c << (16 * i);
    }
    size_t base = (size_t)b * 256 + 2 * j + cg;
    __hip_atomic_store(&hsl[(size_t)(0 * 2 + np) * 4096 + base], p0, __ATOMIC_RELAXED, __HIP_MEMORY_SCOPE_AGENT);
    __hip_atomic_store(&hsl[(size_t)(1 * 2 + np) * 4096 + base], p1, __ATOMIC_RELAXED, __HIP_MEMORY_SCOPE_AGENT);
    __hip_atomic_store(&hsl[(size_t)(2 * 2 + np) * 4096 + base], p2, __ATOMIC_RELAXED, __HIP_MEMORY_SCOPE_AGENT);
  }
  // Manual release: wave-level drain of the data stores, then the flag.
  asm volatile("s_waitcnt vmcnt(0)" ::: "memory");
  if ((tid & 63) == 0) {
    int cg = tid >> 6;
    __hip_atomic_store(&flags[((size_t)np << 8) + 2 * j + cg], fval,
                       __ATOMIC_RELAXED, __HIP_MEMORY_SCOPE_AGENT);
  }
}

struct Frag { short8b h, m, l; };

__global__ __launch_bounds__(256) void xsplit_k(const float* __restrict__ x,
    u16* __restrict__ xh, u16* __restrict__ xm, u16* __restrict__ xl) {
  size_t i = ((size_t)blockIdx.x * 256 + threadIdx.x) * 4;
  float4v v = *(const float4v*)(x + i);
  u64 ph = 0, pm = 0, pl = 0;
  #pragma unroll
  for (int k = 0; k < 4; ++k) {
    float f = v[k];
    u16 a = f2bf(f); float r  = f - bf2f(a);
    u16 b = f2bf(r); float r2 = r - bf2f(b);
    u16 c = f2bf(r2);
    ph |= (u64)a << (16 * k); pm |= (u64)b << (16 * k); pl |= (u64)c << (16 * k);
  }
  *(u64*)(xh + i) = ph; *(u64*)(xm + i) = pm; *(u64*)(xl + i) = pl;
}

__global__ __launch_bounds__(NTHR, 1) void mingru_scan(
    const float* __restrict__ x, const float* __restrict__ h0,
    const float* __restrict__ W_in, const float* __restrict__ b_in,
    const float* __restrict__ W_state, float* __restrict__ out,
    unsigned char* __restrict__ ws, int use_xpre)
{
  extern __shared__ unsigned char smem[];
  u16* WTh = (u16*)smem;                       // [16][WSTR]
  u16* WTl = WTh + 16 * WSTR;                  // [16][WSTR]
  float* Cp    = (float*)(WTl + 16 * WSTR);    // [8][64][4]
  float* gates = Cp + 8 * 64 * 4;              // [16][16]
  float* bias  = gates + 256;                  // [16]

  u64* flags = (u64*)ws;                       // [2][128][2] u64 = 4096 B
  u64* hsl = (u64*)(ws + 4096);                // [3 split][2 slab][16][256] u64
  const u16* xph = (const u16*)(ws + 262144);  // [16][2048][1024] each
  const u16* xpm = xph + (size_t)BB * SS * DD;
  const u16* xpl = xpm + (size_t)BB * SS * DD;

  const int tid = threadIdx.x, j = blockIdx.x;
  const int wid = tid >> 6, l = tid & 63;
  const int mn = l & 15, q = l >> 4;

  // ---- phase 0: h0 publish FIRST (so laggards' W-fill doesn't gate it),
  //      then W slice -> LDS split; bias. Local barrier only. ----
  float hreg = 0.f;
  if (tid < 128) {
    int b = tid & 15, pi = tid >> 4;
    hreg = h0[b * DD + 8 * j + pi];
    publish_h(hsl, flags, 0, 1ull, j, tid, hreg);
  }
  for (int i = tid; i < 16 * EE; i += NTHR) {
    int n = i & 15, k = i >> 4;
    int col = (n < 8) ? (8 * j + n) : (DD + 8 * j + n - 8);
    float w = (k < DD) ? W_in[(size_t)k * EE + col]
                       : W_state[(size_t)(k - DD) * EE + col];
    u16 w1 = f2bf(w);
    u16 w2 = f2bf(w - bf2f(w1));
    WTh[n * WSTR + k] = w1;
    WTl[n * WSTR + k] = w2;
  }
  if (tid < 16) bias[tid] = b_in[(tid < 8) ? (8 * j + tid) : (DD + 8 * j + tid - 8)];
  __syncthreads();

  const int isH  = (wid >= 4);
  const int koff = wid * 256 + q * 8;                       // global k of chunk 0
  const int boff = mn * WSTR + koff;                        // B (LDS) offset
  const int hxb  = mn * 256 + (wid - 4) * 64 + 2 * q;       // h u64 index, chunk 0
  const size_t xrow = (size_t)mn * SS * DD;

  for (int t = 0; t < SS; ++t) {
    const int slab = t & 1;

    // ---- fetch all A fragments for this step (pipelined) ----
    Frag F[8];
    if (isH) {
      // Data-flow gate: lane l polls the one flag for (block, half) pair
      // covering its columns. Wave wid needs d in [(wid-4)*256, +256) ->
      // 32 publisher blocks x 2 halves = 64 flags = one per lane.
      const u64 want = (u64)t + 1;
      const u64* fp = flags + ((size_t)slab << 8) + (size_t)((wid - 4) * 64 + l);
      while (ald(fp) != want) { }
      asm volatile("" ::: "memory");          // keep data loads below the poll
      __builtin_amdgcn_sched_barrier(0);

      const u64* p0 = hsl + (size_t)(0 * 2 + slab) * 4096;
      const u64* p1 = hsl + (size_t)(1 * 2 + slab) * 4096;
      const u64* p2 = hsl + (size_t)(2 * 2 + slab) * 4096;
      #pragma unroll
      for (int c = 0; c < 8; ++c) {
        int ix = hxb + 8 * c;
        union { u64 u[2]; short8b v; } a0, a1, a2;
        a0.u[0] = ald(p0 + ix); a0.u[1] = ald(p0 + ix + 1);
        a1.u[0] = ald(p1 + ix); a1.u[1] = ald(p1 + ix + 1);
        a2.u[0] = ald(p2 + ix); a2.u[1] = ald(p2 + ix + 1);
        F[c].h = a0.v; F[c].m = a1.v; F[c].l = a2.v;
      }
    } else if (use_xpre) {
      size_t o = xrow + (size_t)t * DD + koff;
      #pragma unroll
      for (int c = 0; c < 8; ++c) {
        F[c].h = *(const short8b*)(xph + o + 32 * c);
        F[c].m = *(const short8b*)(xpm + o + 32 * c);
        F[c].l = *(const short8b*)(xpl + o + 32 * c);
      }
    } else {
      const float* xr = x + xrow + (size_t)t * DD + koff;
      #pragma unroll
      for (int c = 0; c < 8; ++c) {
        float vals[8];
        *(float4v*)vals       = *(const float4v*)(xr + 32 * c);
        *(float4v*)(vals + 4) = *(const float4v*)(xr + 32 * c + 4);
        union { u16 s[8]; short8b v; } H, M, L;
        #pragma unroll
        for (int i = 0; i < 8; ++i) {
          float f = vals[i];
          u16 a = f2bf(f); float r  = f - bf2f(a);
          u16 m = f2bf(r); float r2 = r - bf2f(m);
          u16 cc = f2bf(r2);
          H.s[i] = a; M.s[i] = m; L.s[i] = cc;
        }
        F[c].h = H.v; F[c].m = M.v; F[c].l = L.v;
      }
    }

    // ---- MFMA: 5-product split, two accumulator chains (order unchanged) ----
    float4v acc0 = {0.f, 0.f, 0.f, 0.f};
    float4v acc1 = {0.f, 0.f, 0.f, 0.f};
    #pragma unroll
    for (int c = 0; c < 8; c += 2) {
      short8b bh0 = *(const short8b*)(WTh + boff + 32 * c);
      short8b bl0 = *(const short8b*)(WTl + boff + 32 * c);
      short8b bh1 = *(const short8b*)(WTh + boff + 32 * (c + 1));
      short8b bl1 = *(const short8b*)(WTl + boff + 32 * (c + 1));
      acc0 = __builtin_amdgcn_mfma_f32_16x16x32_bf16(F[c].h,     bh0, acc0, 0, 0, 0);
      acc1 = __builtin_amdgcn_mfma_f32_16x16x32_bf16(F[c + 1].h, bh1, acc1, 0, 0, 0);
      acc0 = __builtin_amdgcn_mfma_f32_16x16x32_bf16(F[c].h,     bl0, acc0, 0, 0, 0);
      acc1 = __builtin_amdgcn_mfma_f32_16x16x32_bf16(F[c + 1].h, bl1, acc1, 0, 0, 0);
      acc0 = __builtin_amdgcn_mfma_f32_16x16x32_bf16(F[c].m,     bh0, acc0, 0, 0, 0);
      acc1 = __builtin_amdgcn_mfma_f32_16x16x32_bf16(F[c + 1].m, bh1, acc1, 0, 0, 0);
      acc0 = __builtin_amdgcn_mfma_f32_16x16x32_bf16(F[c].m,     bl0, acc0, 0, 0, 0);
      acc1 = __builtin_amdgcn_mfma_f32_16x16x32_bf16(F[c + 1].m, bl1, acc1, 0, 0, 0);
      acc0 = __builtin_amdgcn_mfma_f32_16x16x32_bf16(F[c].l,     bh0, acc0, 0, 0, 0);
      acc1 = __builtin_amdgcn_mfma_f32_16x16x32_bf16(F[c + 1].l, bh1, acc1, 0, 0, 0);
    }
    acc0.x += acc1.x; acc0.y += acc1.y; acc0.z += acc1.z; acc0.w += acc1.w;

    *(float4v*)(Cp + (wid * 64 + l) * 4) = acc0;
    __syncthreads();

    if (tid < 256) {                 // reduce 8 wave-partials -> gates
      int n = tid & 15, b = tid >> 4;
      int lane = ((b >> 2) << 4) | n, reg = b & 3;
      float s = bias[n];
      #pragma unroll
      for (int w = 0; w < 8; ++w) s += Cp[(w * 64 + lane) * 4 + reg];
      gates[b * 16 + n] = s;
    }
    __syncthreads();

    if (tid < 128) {                 // pointwise + publish (FIRST) + out
      int b = tid & 15, pi = tid >> 4;
      float ug = gates[b * 16 + pi];
      float cg = gates[b * 16 + pi + 8];
      float u  = 1.f / (1.f + __expf(-ug));
      float cv = tanhf(cg);
      hreg = hreg + u * (cv - hreg);
      publish_h(hsl, flags, (t + 1) & 1, (u64)t + 2, j, tid, hreg);
      __builtin_nontemporal_store(hreg,
          out + (size_t)b * SS * DD + (size_t)t * DD + 8 * j + pi);
      if (t == SS - 1) out[(size_t)BB * SS * DD + b * DD + 8 * j + pi] = hreg;
    }
    // no grid barrier: next step's h-waves gate themselves on the flags
  }
}

extern "C" void kernel_launch(void* const* d_in, const int* in_sizes, int n_in,
                              void* d_out, int out_size, void* d_ws, size_t ws_size,
                              hipStream_t stream) {
  (void)in_sizes; (void)n_in; (void)out_size;
  const float* x    = (const float*)d_in[0];
  const float* h0   = (const float*)d_in[1];
  const float* W_in = (const float*)d_in[2];
  const float* b_in = (const float*)d_in[3];
  const float* W_st = (const float*)d_in[4];
  float* out = (float*)d_out;

  size_t need = 262144 + 3 * (size_t)BB * SS * DD * 2;   // ~192.3 MB
  int use_xpre = (ws_size >= need) ? 1 : 0;

  const int smem_bytes = (2 * 16 * WSTR) * 2 + (8 * 64 * 4 + 256 + 16) * 4; // 140,864
  static int attr_set = 0;
  if (!attr_set) {
    hipFuncSetAttribute((const void*)mingru_scan,
                        hipFuncAttributeMaxDynamicSharedMemorySize, smem_bytes);
    attr_set = 1;
  }

  hipMemsetAsync(d_ws, 0, 4096, stream);   // clear step flags
  if (use_xpre) {
    u16* xh = (u16*)((unsigned char*)d_ws + 262144);
    u16* xm = xh + (size_t)BB * SS * DD;
    u16* xl = xm + (size_t)BB * SS * DD;
    hipLaunchKernelGGL(xsplit_k, dim3(32768), dim3(256), 0, stream, x, xh, xm, xl);
  }
  hipLaunchKernelGGL(mingru_scan, dim3(NBLK), dim3(NTHR), smem_bytes, stream,
                     x, h0, W_in, b_in, W_st, out, (unsigned char*)d_ws, use_xpre);
}

// Round 3
// 15313.440 us; speedup vs baseline: 1.4689x; 1.3939x over previous
//
#include <hip/hip_runtime.h>
#include <cstdint>
#include <cstddef>

// MinGRU scan, round 5 (re-run; round-2 bench lost to GPU acquisition timeout):
// XCD-local recurrence.
//  - gx = x @ W_in precomputed by an LDS-free MFMA GEMM (W pre-transposed+split).
//  - Scan runs on 32 persistent blocks CLAIMED ON ONE XCD (HW_REG_XCC_ID +
//    pigeonhole over 256 launched blocks). h state exchanged as fp32 through
//    the XCD-shared L2: plain stores (write-through to L2) + volatile loads
//    (sc0, L1-bypass). Only the per-step ready FLAG uses agent-scope atomics.
//  - W_state slice lives entirely in registers (no per-step W traffic).
// Fallback: if ws_size < ~273 MB, run the round-4 kernel unchanged.

#define BB 16
#define SS 2048
#define DD 1024
#define EE 2048
#define NBLK 128
#define NTHR 512
#define WSTR 2056

typedef __attribute__((ext_vector_type(8))) short short8b;
typedef __attribute__((ext_vector_type(4))) float float4v;
typedef unsigned long long u64;
typedef unsigned int u32;
typedef unsigned short u16;

__device__ __forceinline__ u16 f2bf(float f) {
  unsigned u = __float_as_uint(f);
  return (u16)((u + 0x7FFFu + ((u >> 16) & 1u)) >> 16);
}
__device__ __forceinline__ float bf2f(u16 s) { return __uint_as_float(((unsigned)s) << 16); }
__device__ __forceinline__ u64 ald(const u64* p) {
  return __hip_atomic_load(p, __ATOMIC_RELAXED, __HIP_MEMORY_SCOPE_AGENT);
}
__device__ __forceinline__ u32 ald32(const u32* p) {
  return __hip_atomic_load(p, __ATOMIC_RELAXED, __HIP_MEMORY_SCOPE_AGENT);
}
__device__ __forceinline__ void ast32(u32* p, u32 v) {
  __hip_atomic_store(p, v, __ATOMIC_RELAXED, __HIP_MEMORY_SCOPE_AGENT);
}

// Truncation-based 3-way bf16 split of 8 fp32 (cheap: and/sub, residual ~2^-24).
__device__ __forceinline__ void split3(const float* v, short8b& H, short8b& M, short8b& L) {
  union { u16 s[8]; short8b v8; } h_, m_, l_;
  #pragma unroll
  for (int i = 0; i < 8; ++i) {
    float f = v[i];
    unsigned uf = __float_as_uint(f);
    h_.s[i] = (u16)(uf >> 16);
    float r = f - __uint_as_float(uf & 0xFFFF0000u);
    unsigned ur = __float_as_uint(r);
    m_.s[i] = (u16)(ur >> 16);
    float r2 = r - __uint_as_float(ur & 0xFFFF0000u);
    l_.s[i] = f2bf(r2);
  }
  H = h_.v8; M = m_.v8; L = l_.v8;
}

// ====================== NEW PATH ======================

// Transpose + 2-way split W [1024][2048] fp32 -> WT hi/lo [2048][1024] bf16.
__global__ __launch_bounds__(256) void wsplit_k(const float* __restrict__ src,
    u16* __restrict__ dsth, u16* __restrict__ dstl) {
  __shared__ u16 th[64][65];
  __shared__ u16 tl[64][65];
  const int tid = threadIdx.x;
  const int kg = blockIdx.x & 15, eg = blockIdx.x >> 4;
  const int k0 = kg * 64, e0 = eg * 64;
  #pragma unroll
  for (int it = 0; it < 16; ++it) {
    int idx = it * 256 + tid;
    int kk = idx >> 6, ee = idx & 63;
    float f = src[(size_t)(k0 + kk) * EE + e0 + ee];
    u16 w1 = f2bf(f);
    u16 w2 = f2bf(f - bf2f(w1));
    th[kk][ee] = w1; tl[kk][ee] = w2;
  }
  __syncthreads();
  #pragma unroll
  for (int it = 0; it < 16; ++it) {
    int idx = it * 256 + tid;
    int ee = idx >> 6, kk = idx & 63;
    dsth[(size_t)(e0 + ee) * 1024 + k0 + kk] = th[kk][ee];
    dstl[(size_t)(e0 + ee) * 1024 + k0 + kk] = tl[kk][ee];
  }
}

// gx[t][b][e] = sum_k x[b][t][k] * W_in[k][e]   (no bias; added in scan)
// LDS-free: A (x) split on the fly, B from pre-transposed WinT hi/lo.
// Block = 512 thr, 8 waves; wave handles 2 t-steps x 128 cols; 2048 blocks.
__global__ __launch_bounds__(512, 2) void gx_gemm(const float* __restrict__ x,
    const u16* __restrict__ Bh, const u16* __restrict__ Bl, float* __restrict__ gx)
{
  const int tid = threadIdx.x, wid = tid >> 6, l = tid & 63;
  const int mn = l & 15, q = l >> 4;
  const int nb = blockIdx.x >> 7;     // 0..15  (consecutive blocks share n-slice -> L2)
  const int mb = blockIdx.x & 127;    // 0..127
  const int t0 = mb * 16 + wid * 2;
  const int e0 = nb * 128;
  const float* xp0 = x + ((size_t)mn * SS + t0) * DD;
  float4v acc[2][8];
  #pragma unroll
  for (int a = 0; a < 2; ++a)
    #pragma unroll
    for (int n2 = 0; n2 < 8; ++n2) acc[a][n2] = (float4v){0.f, 0.f, 0.f, 0.f};

  for (int kc = 0; kc < 32; ++kc) {
    const int k0 = kc * 32 + q * 8;
    float a0[8], a1[8];
    *(float4v*)(a0)     = *(const float4v*)(xp0 + k0);
    *(float4v*)(a0 + 4) = *(const float4v*)(xp0 + k0 + 4);
    *(float4v*)(a1)     = *(const float4v*)(xp0 + DD + k0);
    *(float4v*)(a1 + 4) = *(const float4v*)(xp0 + DD + k0 + 4);
    short8b H0, M0, L0, H1, M1, L1;
    split3(a0, H0, M0, L0);
    split3(a1, H1, M1, L1);
    #pragma unroll
    for (int nt = 0; nt < 8; ++nt) {
      const size_t be = ((size_t)(e0 + nt * 16 + mn) << 10) + k0;
      short8b bh = *(const short8b*)(Bh + be);
      short8b bl = *(const short8b*)(Bl + be);
      acc[0][nt] = __builtin_amdgcn_mfma_f32_16x16x32_bf16(H0, bh, acc[0][nt], 0, 0, 0);
      acc[0][nt] = __builtin_amdgcn_mfma_f32_16x16x32_bf16(H0, bl, acc[0][nt], 0, 0, 0);
      acc[0][nt] = __builtin_amdgcn_mfma_f32_16x16x32_bf16(M0, bh, acc[0][nt], 0, 0, 0);
      acc[0][nt] = __builtin_amdgcn_mfma_f32_16x16x32_bf16(M0, bl, acc[0][nt], 0, 0, 0);
      acc[0][nt] = __builtin_amdgcn_mfma_f32_16x16x32_bf16(L0, bh, acc[0][nt], 0, 0, 0);
      acc[1][nt] = __builtin_amdgcn_mfma_f32_16x16x32_bf16(H1, bh, acc[1][nt], 0, 0, 0);
      acc[1][nt] = __builtin_amdgcn_mfma_f32_16x16x32_bf16(H1, bl, acc[1][nt], 0, 0, 0);
      acc[1][nt] = __builtin_amdgcn_mfma_f32_16x16x32_bf16(M1, bh, acc[1][nt], 0, 0, 0);
      acc[1][nt] = __builtin_amdgcn_mfma_f32_16x16x32_bf16(M1, bl, acc[1][nt], 0, 0, 0);
      acc[1][nt] = __builtin_amdgcn_mfma_f32_16x16x32_bf16(L1, bh, acc[1][nt], 0, 0, 0);
    }
  }
  #pragma unroll
  for (int tt = 0; tt < 2; ++tt)
    #pragma unroll
    for (int nt = 0; nt < 8; ++nt)
      #pragma unroll
      for (int i = 0; i < 4; ++i)
        gx[((size_t)(t0 + tt) * 16 + (q * 4 + i)) * 2048 + e0 + nt * 16 + mn] = acc[tt][nt][i];
}

// Persistent XCD-local scan. 256 blocks launched; 32 on one XCD claim the work.
// Worker r owns h-cols [32r,32r+32) -> gate cols {32r..}, {1024+32r..}.
// ws layout: cnt[8] @0 (64B apart), winner @512, flags @4096 (2 slab x 32 x 64B),
// hsl fp32 [2][16][1024] @8192.
__global__ __launch_bounds__(512, 2) void mingru_scan_xcd(
    const float* __restrict__ h0, const float* __restrict__ b_in,
    const u16* __restrict__ Bh, const u16* __restrict__ Bl,
    const float* __restrict__ gx, float* __restrict__ out,
    unsigned char* __restrict__ ws)
{
  __shared__ float Cp[8][64][20];
  __shared__ int srank;
  const int tid = threadIdx.x;

  if (tid == 0) {
    int x;
    asm volatile("s_getreg_b32 %0, hwreg(HW_REG_XCC_ID)" : "=s"(x));
    x &= 7;
    int* cnt = (int*)ws;
    int* winner = (int*)(ws + 512);
    int tk = __hip_atomic_fetch_add(&cnt[x * 16], 1, __ATOMIC_RELAXED, __HIP_MEMORY_SCOPE_AGENT);
    int rank = -1;
    if (tk < 32) {
      if (tk == 31) {
        int exp = 0;
        __hip_atomic_compare_exchange_strong(winner, &exp, x + 1,
            __ATOMIC_RELAXED, __ATOMIC_RELAXED, __HIP_MEMORY_SCOPE_AGENT);
      }
      int w;
      while ((w = __hip_atomic_load(winner, __ATOMIC_RELAXED, __HIP_MEMORY_SCOPE_AGENT)) == 0)
        __builtin_amdgcn_s_sleep(8);
      if (w == x + 1) rank = tk;
    }
    srank = rank;
  }
  __syncthreads();
  const int r = srank;
  if (r < 0) return;

  const int wid = tid >> 6, l = tid & 63, mn = l & 15, q = l >> 4;
  u32* flags = (u32*)(ws + 4096);          // flag(slab,j) at [(slab*32+j)*16]
  float* hsl = (float*)(ws + 8192);        // [2][16][1024]

  // W_state slice -> registers (loaded once, strided from WstT).
  short8b bh[4][4], bl[4][4];
  const int ebase[4] = {32 * r, 32 * r + 16, 1024 + 32 * r, 1040 + 32 * r};
  #pragma unroll
  for (int nt = 0; nt < 4; ++nt) {
    const int e = ebase[nt] + mn;
    #pragma unroll
    for (int kc = 0; kc < 4; ++kc) {
      const int k = wid * 128 + kc * 32 + q * 8;
      const size_t o = ((size_t)e << 10) + k;
      bh[nt][kc] = *(const short8b*)(Bh + o);
      bl[nt][kc] = *(const short8b*)(Bl + o);
    }
  }

  // Per-thread h ownership: (b, pi) -> col = 32r + pi.
  const int b = tid >> 5, pi = tid & 31;
  const int col = 32 * r + pi;
  const float bias_u = b_in[col];
  const float bias_c = b_in[1024 + col];
  float hreg = h0[b * DD + col];

  // publish h0 into slab 0
  hsl[b * 1024 + col] = hreg;
  asm volatile("s_waitcnt vmcnt(0)" ::: "memory");
  __syncthreads();
  if (tid == 0) ast32(&flags[(0 * 32 + r) * 16], 1u);

  const int lu = (b >> 2) * 16 + (pi & 15);
  const int su = (pi >> 4) * 4 + (b & 3);

  for (int t = 0; t < SS; ++t) {
    const int slab = t & 1;

    // gx loads issued early (overlap the poll)
    const size_t gxo = ((size_t)t * 16 + b) * 2048 + col;
    const float gxu = gx[gxo];
    const float gxc = gx[gxo + 1024];

    // wave-level poll: this wave's k-range [128*wid, +128) = producers 4wid..4wid+3
    if (l < 4) {
      const u32* fp = &flags[(slab * 32 + wid * 4 + l) * 16];
      while (ald32(fp) < (u32)(t + 1)) {}
    }
    asm volatile("" ::: "memory");
    __builtin_amdgcn_sched_barrier(0);

    // h fetch (volatile -> sc0, L2-served) + split + MFMA
    float4v acc[4];
    #pragma unroll
    for (int nt = 0; nt < 4; ++nt) acc[nt] = (float4v){0.f, 0.f, 0.f, 0.f};
    #pragma unroll
    for (int kc = 0; kc < 4; ++kc) {
      const int k0 = wid * 128 + kc * 32 + q * 8;
      const volatile u64* hp = (const volatile u64*)(hsl + slab * 16384 + mn * 1024 + k0);
      union { u64 u[4]; float f[8]; } A;
      A.u[0] = hp[0]; A.u[1] = hp[1]; A.u[2] = hp[2]; A.u[3] = hp[3];
      short8b hh, hm, hl;
      split3(A.f, hh, hm, hl);
      #pragma unroll
      for (int nt = 0; nt < 4; ++nt) {
        acc[nt] = __builtin_amdgcn_mfma_f32_16x16x32_bf16(hh, bh[nt][kc], acc[nt], 0, 0, 0);
        acc[nt] = __builtin_amdgcn_mfma_f32_16x16x32_bf16(hh, bl[nt][kc], acc[nt], 0, 0, 0);
        acc[nt] = __builtin_amdgcn_mfma_f32_16x16x32_bf16(hm, bh[nt][kc], acc[nt], 0, 0, 0);
        acc[nt] = __builtin_amdgcn_mfma_f32_16x16x32_bf16(hm, bl[nt][kc], acc[nt], 0, 0, 0);
        acc[nt] = __builtin_amdgcn_mfma_f32_16x16x32_bf16(hl, bh[nt][kc], acc[nt], 0, 0, 0);
      }
    }

    *(float4v*)&Cp[wid][l][0]  = acc[0];
    *(float4v*)&Cp[wid][l][4]  = acc[1];
    *(float4v*)&Cp[wid][l][8]  = acc[2];
    *(float4v*)&Cp[wid][l][12] = acc[3];
    __syncthreads();

    // reduce 8 wave-partials for this thread's (u, c) pair + pointwise
    float s_u = bias_u + gxu, s_c = bias_c + gxc;
    #pragma unroll
    for (int w = 0; w < 8; ++w) {
      s_u += Cp[w][lu][su];
      s_c += Cp[w][lu][su + 8];
    }
    const float ug = 1.f / (1.f + __expf(-s_u));
    const float cv = tanhf(s_c);
    hreg = hreg + ug * (cv - hreg);

    // publish (L2) -> drain -> barrier -> flag (L3)
    const int ns = slab ^ 1;
    hsl[ns * 16384 + b * 1024 + col] = hreg;
    asm volatile("s_waitcnt vmcnt(0)" ::: "memory");
    __syncthreads();
    if (tid == 0) ast32(&flags[(ns * 32 + r) * 16], (u32)(t + 2));

    __builtin_nontemporal_store(hreg, out + ((size_t)b * SS + t) * DD + col);
    if (t == SS - 1) out[(size_t)BB * SS * DD + b * DD + col] = hreg;
  }
}

// ====================== OLD PATH (round-4 fallback) ======================

__device__ __forceinline__ void publish_h(u64* hsl, u64* flags, int np, u64 fval,
                                          int j, int tid, float hn) {
  int src = (tid & 15);
  float g1 = __shfl(hn, src + 16, 64);
  float g2 = __shfl(hn, src + 32, 64);
  float g3 = __shfl(hn, src + 48, 64);
  if ((tid & 63) < 16) {
    int b = tid & 15, cg = tid >> 6;
    float vals[4] = {hn, g1, g2, g3};
    u64 p0 = 0, p1 = 0, p2 = 0;
    #pragma unroll
    for (int i = 0; i < 4; ++i) {
      float f = vals[i];
      u16 a = f2bf(f); float rr = f - bf2f(a);
      u16 m = f2bf(rr); float r2 = rr - bf2f(m);
      u16 c = f2bf(r2);
      p0 |= (u64)a << (16 * i); p1 |= (u64)m << (16 * i); p2 |= (u64)c << (16 * i);
    }
    size_t base = (size_t)b * 256 + 2 * j + cg;
    __hip_atomic_store(&hsl[(size_t)(0 * 2 + np) * 4096 + base], p0, __ATOMIC_RELAXED, __HIP_MEMORY_SCOPE_AGENT);
    __hip_atomic_store(&hsl[(size_t)(1 * 2 + np) * 4096 + base], p1, __ATOMIC_RELAXED, __HIP_MEMORY_SCOPE_AGENT);
    __hip_atomic_store(&hsl[(size_t)(2 * 2 + np) * 4096 + base], p2, __ATOMIC_RELAXED, __HIP_MEMORY_SCOPE_AGENT);
  }
  asm volatile("s_waitcnt vmcnt(0)" ::: "memory");
  if ((tid & 63) == 0) {
    int cg = tid >> 6;
    __hip_atomic_store(&flags[((size_t)np << 8) + 2 * j + cg], fval,
                       __ATOMIC_RELAXED, __HIP_MEMORY_SCOPE_AGENT);
  }
}

struct Frag { short8b h, m, l; };

__global__ __launch_bounds__(256) void xsplit_k(const float* __restrict__ x,
    u16* __restrict__ xh, u16* __restrict__ xm, u16* __restrict__ xl) {
  size_t i = ((size_t)blockIdx.x * 256 + threadIdx.x) * 4;
  float4v v = *(const float4v*)(x + i);
  u64 ph = 0, pm = 0, pl = 0;
  #pragma unroll
  for (int k = 0; k < 4; ++k) {
    float f = v[k];
    u16 a = f2bf(f); float rr = f - bf2f(a);
    u16 bb = f2bf(rr); float r2 = rr - bf2f(bb);
    u16 c = f2bf(r2);
    ph |= (u64)a << (16 * k); pm |= (u64)bb << (16 * k); pl |= (u64)c << (16 * k);
  }
  *(u64*)(xh + i) = ph; *(u64*)(xm + i) = pm; *(u64*)(xl + i) = pl;
}

__global__ __launch_bounds__(NTHR, 1) void mingru_scan(
    const float* __restrict__ x, const float* __restrict__ h0,
    const float* __restrict__ W_in, const float* __restrict__ b_in,
    const float* __restrict__ W_state, float* __restrict__ out,
    unsigned char* __restrict__ ws, int use_xpre)
{
  extern __shared__ unsigned char smem[];
  u16* WTh = (u16*)smem;
  u16* WTl = WTh + 16 * WSTR;
  float* Cp    = (float*)(WTl + 16 * WSTR);
  float* gates = Cp + 8 * 64 * 4;
  float* bias  = gates + 256;

  u64* flags = (u64*)ws;
  u64* hsl = (u64*)(ws + 4096);
  const u16* xph = (const u16*)(ws + 262144);
  const u16* xpm = xph + (size_t)BB * SS * DD;
  const u16* xpl = xpm + (size_t)BB * SS * DD;

  const int tid = threadIdx.x, j = blockIdx.x;
  const int wid = tid >> 6, l = tid & 63;
  const int mn = l & 15, q = l >> 4;

  float hreg = 0.f;
  if (tid < 128) {
    int b = tid & 15, pi = tid >> 4;
    hreg = h0[b * DD + 8 * j + pi];
    publish_h(hsl, flags, 0, 1ull, j, tid, hreg);
  }
  for (int i = tid; i < 16 * EE; i += NTHR) {
    int n = i & 15, k = i >> 4;
    int colw = (n < 8) ? (8 * j + n) : (DD + 8 * j + n - 8);
    float w = (k < DD) ? W_in[(size_t)k * EE + colw]
                       : W_state[(size_t)(k - DD) * EE + colw];
    u16 w1 = f2bf(w);
    u16 w2 = f2bf(w - bf2f(w1));
    WTh[n * WSTR + k] = w1;
    WTl[n * WSTR + k] = w2;
  }
  if (tid < 16) bias[tid] = b_in[(tid < 8) ? (8 * j + tid) : (DD + 8 * j + tid - 8)];
  __syncthreads();

  const int isH  = (wid >= 4);
  const int koff = wid * 256 + q * 8;
  const int boff = mn * WSTR + koff;
  const int hxb  = mn * 256 + (wid - 4) * 64 + 2 * q;
  const size_t xrow = (size_t)mn * SS * DD;

  for (int t = 0; t < SS; ++t) {
    const int slab = t & 1;
    Frag F[8];
    if (isH) {
      const u64 want = (u64)t + 1;
      const u64* fp = flags + ((size_t)slab << 8) + (size_t)((wid - 4) * 64 + l);
      while (ald(fp) != want) { }
      asm volatile("" ::: "memory");
      __builtin_amdgcn_sched_barrier(0);

      const u64* p0 = hsl + (size_t)(0 * 2 + slab) * 4096;
      const u64* p1 = hsl + (size_t)(1 * 2 + slab) * 4096;
      const u64* p2 = hsl + (size_t)(2 * 2 + slab) * 4096;
      #pragma unroll
      for (int c = 0; c < 8; ++c) {
        int ix = hxb + 8 * c;
        union { u64 u[2]; short8b v; } a0, a1, a2;
        a0.u[0] = ald(p0 + ix); a0.u[1] = ald(p0 + ix + 1);
        a1.u[0] = ald(p1 + ix); a1.u[1] = ald(p1 + ix + 1);
        a2.u[0] = ald(p2 + ix); a2.u[1] = ald(p2 + ix + 1);
        F[c].h = a0.v; F[c].m = a1.v; F[c].l = a2.v;
      }
    } else if (use_xpre) {
      size_t o = xrow + (size_t)t * DD + koff;
      #pragma unroll
      for (int c = 0; c < 8; ++c) {
        F[c].h = *(const short8b*)(xph + o + 32 * c);
        F[c].m = *(const short8b*)(xpm + o + 32 * c);
        F[c].l = *(const short8b*)(xpl + o + 32 * c);
      }
    } else {
      const float* xr = x + xrow + (size_t)t * DD + koff;
      #pragma unroll
      for (int c = 0; c < 8; ++c) {
        float vals[8];
        *(float4v*)vals       = *(const float4v*)(xr + 32 * c);
        *(float4v*)(vals + 4) = *(const float4v*)(xr + 32 * c + 4);
        union { u16 s[8]; short8b v; } H, M, L;
        #pragma unroll
        for (int i = 0; i < 8; ++i) {
          float f = vals[i];
          u16 a = f2bf(f); float rr = f - bf2f(a);
          u16 m = f2bf(rr); float r2 = rr - bf2f(m);
          u16 cc = f2bf(r2);
          H.s[i] = a; M.s[i] = m; L.s[i] = cc;
        }
        F[c].h = H.v; F[c].m = M.v; F[c].l = L.v;
      }
    }

    float4v acc0 = {0.f, 0.f, 0.f, 0.f};
    float4v acc1 = {0.f, 0.f, 0.f, 0.f};
    #pragma unroll
    for (int c = 0; c < 8; c += 2) {
      short8b bh0 = *(const short8b*)(WTh + boff + 32 * c);
      short8b bl0 = *(const short8b*)(WTl + boff + 32 * c);
      short8b bh1 = *(const short8b*)(WTh + boff + 32 * (c + 1));
      short8b bl1 = *(const short8b*)(WTl + boff + 32 * (c + 1));
      acc0 = __builtin_amdgcn_mfma_f32_16x16x32_bf16(F[c].h,     bh0, acc0, 0, 0, 0);
      acc1 = __builtin_amdgcn_mfma_f32_16x16x32_bf16(F[c + 1].h, bh1, acc1, 0, 0, 0);
      acc0 = __builtin_amdgcn_mfma_f32_16x16x32_bf16(F[c].h,     bl0, acc0, 0, 0, 0);
      acc1 = __builtin_amdgcn_mfma_f32_16x16x32_bf16(F[c + 1].h, bl1, acc1, 0, 0, 0);
      acc0 = __builtin_amdgcn_mfma_f32_16x16x32_bf16(F[c].m,     bh0, acc0, 0, 0, 0);
      acc1 = __builtin_amdgcn_mfma_f32_16x16x32_bf16(F[c + 1].m, bh1, acc1, 0, 0, 0);
      acc0 = __builtin_amdgcn_mfma_f32_16x16x32_bf16(F[c].m,     bl0, acc0, 0, 0, 0);
      acc1 = __builtin_amdgcn_mfma_f32_16x16x32_bf16(F[c + 1].m, bl1, acc1, 0, 0, 0);
      acc0 = __builtin_amdgcn_mfma_f32_16x16x32_bf16(F[c].l,     bh0, acc0, 0, 0, 0);
      acc1 = __builtin_amdgcn_mfma_f32_16x16x32_bf16(F[c + 1].l, bh1, acc1, 0, 0, 0);
    }
    acc0.x += acc1.x; acc0.y += acc1.y; acc0.z += acc1.z; acc0.w += acc1.w;

    *(float4v*)(Cp + (wid * 64 + l) * 4) = acc0;
    __syncthreads();

    if (tid < 256) {
      int n = tid & 15, bb2 = tid >> 4;
      int lane = ((bb2 >> 2) << 4) | n, reg = bb2 & 3;
      float s = bias[n];
      #pragma unroll
      for (int w = 0; w < 8; ++w) s += Cp[(w * 64 + lane) * 4 + reg];
      gates[bb2 * 16 + n] = s;
    }
    __syncthreads();

    if (tid < 128) {
      int bb2 = tid & 15, pi = tid >> 4;
      float ug = gates[bb2 * 16 + pi];
      float cg = gates[bb2 * 16 + pi + 8];
      float u  = 1.f / (1.f + __expf(-ug));
      float cv = tanhf(cg);
      hreg = hreg + u * (cv - hreg);
      publish_h(hsl, flags, (t + 1) & 1, (u64)t + 2, j, tid, hreg);
      __builtin_nontemporal_store(hreg,
          out + (size_t)bb2 * SS * DD + (size_t)t * DD + 8 * j + pi);
      if (t == SS - 1) out[(size_t)BB * SS * DD + bb2 * DD + 8 * j + pi] = hreg;
    }
  }
}

// ====================== LAUNCHER ======================

extern "C" void kernel_launch(void* const* d_in, const int* in_sizes, int n_in,
                              void* d_out, int out_size, void* d_ws, size_t ws_size,
                              hipStream_t stream) {
  (void)in_sizes; (void)n_in; (void)out_size;
  const float* x    = (const float*)d_in[0];
  const float* h0   = (const float*)d_in[1];
  const float* W_in = (const float*)d_in[2];
  const float* b_in = (const float*)d_in[3];
  const float* W_st = (const float*)d_in[4];
  float* out = (float*)d_out;

  const size_t need_new = ((size_t)17 << 20) + (size_t)BB * SS * EE * 4;  // ~273 MB
  if (ws_size >= need_new) {
    unsigned char* w = (unsigned char*)d_ws;
    u16* WinTh = (u16*)(w + ((size_t)1 << 20));
    u16* WinTl = (u16*)(w + ((size_t)5 << 20));
    u16* WstTh = (u16*)(w + ((size_t)9 << 20));
    u16* WstTl = (u16*)(w + ((size_t)13 << 20));
    float* gx  = (float*)(w + ((size_t)17 << 20));

    hipMemsetAsync(w, 0, 8192, stream);
    hipLaunchKernelGGL(wsplit_k, dim3(512), dim3(256), 0, stream, W_in, WinTh, WinTl);
    hipLaunchKernelGGL(wsplit_k, dim3(512), dim3(256), 0, stream, W_st, WstTh, WstTl);
    hipLaunchKernelGGL(gx_gemm, dim3(2048), dim3(512), 0, stream, x, WinTh, WinTl, gx);
    hipLaunchKernelGGL(mingru_scan_xcd, dim3(256), dim3(512), 0, stream,
                       h0, b_in, WstTh, WstTl, gx, out, w);
    return;
  }

  // ---- fallback: round-4 path ----
  size_t need = 262144 + 3 * (size_t)BB * SS * DD * 2;
  int use_xpre = (ws_size >= need) ? 1 : 0;

  const int smem_bytes = (2 * 16 * WSTR) * 2 + (8 * 64 * 4 + 256 + 16) * 4;
  static int attr_set = 0;
  if (!attr_set) {
    hipFuncSetAttribute((const void*)mingru_scan,
                        hipFuncAttributeMaxDynamicSharedMemorySize, smem_bytes);
    attr_set = 1;
  }

  hipMemsetAsync(d_ws, 0, 4096, stream);
  if (use_xpre) {
    u16* xh = (u16*)((unsigned char*)d_ws + 262144);
    u16* xm = xh + (size_t)BB * SS * DD;
    u16* xl = xm + (size_t)BB * SS * DD;
    hipLaunchKernelGGL(xsplit_k, dim3(32768), dim3(256), 0, stream, x, xh, xm, xl);
  }
  hipLaunchKernelGGL(mingru_scan, dim3(NBLK), dim3(NTHR), smem_bytes, stream,
                     x, h0, W_in, b_in, W_st, out, (unsigned char*)d_ws, use_xpre);
}